// Round 16
// baseline (449.936 us; speedup 1.0000x reference)
//
#include <hip/hip_runtime.h>
#include <hip/hip_cooperative_groups.h>

namespace cg = cooperative_groups;

// DigiCaps dynamic routing — single fused cooperative kernel.
// inputs [512,1152,8] f32, W [10,1152,16,8] f32, out v [512,10,16] f32.
// u_hat[b,j,i,d] = sum_k x[b,i,k] W[j,i,d,k]; logits b_t = u_hat . vsum.
//
// R12-R15 forensics: 3-pass structure pinned at ~40-50us/pass (~34K cy/wave
// vs ~3K instruction budget) regardless of inner-loop changes — the cost is
// structural (per-kernel staging + ramp/drain + partials round-trip). R16:
// ONE cooperative kernel: stage W/x tiles once (block = 64 b x 18 i, 65.9KB
// LDS, 2 blocks/CU, grid 512 = capacity), then 3 iterations separated by
// grid.sync(), with squash done in-kernel (threads gt<81920, running vsum
// in a register). iter0 = K=32-packed MFMA chain (4 i per MFMA + 2-i tail);
// iter1/2 isolate each i by masking B (kg==q ? xv : 0). Fallback to the
// proven R15 3-pass path if cooperative launch fails.
// MFMA f32_16x16x32_bf16, C-layout: lane&15=b(col), (lane>>4)*4+reg=d(row).
// absmax ~4e-3 (threshold 17.5e-3).

#define NB 512
#define NI 1152
#define NJ 10
#define ND 16

typedef short          bf16x8 __attribute__((ext_vector_type(8)));
typedef unsigned short u16x8  __attribute__((ext_vector_type(8)));
typedef float          f32x4  __attribute__((ext_vector_type(4)));

constexpr float EPS_ = 1e-7f;

constexpr size_t XB_ELEMS = (size_t)NB * NI * 8;       // bf16
constexpr size_t WB_ELEMS = (size_t)NJ * NI * ND * 8;  // bf16
constexpr int    XQ = 1179648;                         // x float4 quads
constexpr int    WQ = 368640;                          // W float4 quads
constexpr int    NIGC = 64;                            // fused: i-chunks of 18
constexpr int    NIGB = 144;                           // fallback: i-groups of 8

__device__ inline unsigned short f2bf(float f) {   // RNE f32->bf16
    unsigned u = __float_as_uint(f);
    return (unsigned short)((u + 0x7fffu + ((u >> 16) & 1u)) >> 16);
}
__device__ inline float bf2f(unsigned short u) {
    return __uint_as_float((unsigned)u << 16);
}

__global__ __launch_bounds__(256)
void conv_bf16(const float* __restrict__ x, const float* __restrict__ Wg,
               unsigned short* __restrict__ xb, unsigned short* __restrict__ wb)
{
    int t = blockIdx.x * 256 + threadIdx.x;
    if (t < XQ) {
        float4 v = ((const float4*)x)[t];
        ushort4 o; o.x=f2bf(v.x); o.y=f2bf(v.y); o.z=f2bf(v.z); o.w=f2bf(v.w);
        ((ushort4*)xb)[t] = o;
    } else if (t - XQ < WQ) {
        int u = t - XQ;
        float4 v = ((const float4*)Wg)[u];
        ushort4 o; o.x=f2bf(v.x); o.y=f2bf(v.y); o.z=f2bf(v.z); o.w=f2bf(v.w);
        ((ushort4*)wb)[u] = o;
    }
}

// ============================ FUSED (cooperative) ============================

__global__ __launch_bounds__(256, 2)
void caps_fused(const unsigned short* __restrict__ xb,
                const unsigned short* __restrict__ wb,
                unsigned short* __restrict__ part,   // [64][512][160] bf16, 10.5MB
                float* __restrict__ vsum_g,          // [512][160] f32
                float* __restrict__ out)
{
    // smem (bytes): [0,46368) wl 18 rows x 161 granules [j*16+d];
    // [46368,65824) xl 64 rows x 19 granules; [65824,65840) zp.
    __shared__ __align__(16) char smem[65840];
    unsigned short* wl = (unsigned short*)smem;
    unsigned short* xl = (unsigned short*)(smem + 46368);
    unsigned short* zp = (unsigned short*)(smem + 65824);

    const int tid = threadIdx.x, lane = tid & 63, w = tid >> 6;
    const int bl = lane & 15, kg = lane >> 4;
    const int blk = blockIdx.x;
    const int bg = blk & 7, igc = blk >> 3;
    const int i0 = igc * 18, b0 = bg * 64;
    const int brow = w * 16 + bl;
    const int b  = b0 + brow;
    const int gt = blk * 256 + tid;

    if (tid < 8) zp[tid] = 0;

    // ---- stage W: 2880 granules, slot = il*161 + (j*16+d)
#pragma unroll
    for (int r = 0; r < 12; ++r) {
        int g = tid + r * 256;
        if (g < 2880) {
            int il = g / 160, rem = g - il * 160;
            *(u16x8*)(wl + (il * 161 + rem) * 8) = *(const u16x8*)(
                wb + ((size_t)(rem >> 4) * NI + (i0 + il)) * 128 + (rem & 15) * 8);
        }
    }
    // ---- stage x: 1152 granules, slot = br*19 + il
#pragma unroll
    for (int r = 0; r < 5; ++r) {
        int g = tid + r * 256;
        if (g < 1152) {
            int br = g / 18, il = g - br * 18;
            *(u16x8*)(xl + (br * 19 + il) * 8) = *(const u16x8*)(
                xb + ((size_t)(b0 + br) * NI + i0 + il) * 8);
        }
    }
    __syncthreads();

    cg::grid_group grid = cg::this_grid();

    const f32x4  zero  = {0.f, 0.f, 0.f, 0.f};
    const bf16x8 zerob = {0, 0, 0, 0, 0, 0, 0, 0};
    float vr = 0.f;   // running vsum for this squash-thread's element

    for (int iter = 0; iter < 3; ++iter) {
        const bool fused = (iter > 0);

        f32x4 vs[NJ];
        if (fused) {
#pragma unroll
            for (int j = 0; j < NJ; ++j)
                vs[j] = *(const f32x4*)(vsum_g + (size_t)b * 160 + j * 16 + kg * 4);
        }

        f32x4 sacc[NJ];
#pragma unroll
        for (int j = 0; j < NJ; ++j) sacc[j] = zero;

#pragma unroll
        for (int t4 = 0; t4 < 5; ++t4) {
            const int nq = (t4 == 4) ? 2 : 4;
            const int il = t4 * 4 + kg;
            const bool realA = (il < 18);

            bf16x8 afull[NJ];
#pragma unroll
            for (int j = 0; j < NJ; ++j) {
                const unsigned short* ap = realA
                    ? (wl + (il * 161 + j * 16 + bl) * 8) : zp;
                afull[j] = *(const bf16x8*)ap;
            }
            const int xil = (t4 == 4) ? (16 + (kg & 1)) : il;
            bf16x8 xv = *(const bf16x8*)(xl + (brow * 19 + xil) * 8);

            if (!fused) {
                // K=32 contracts the pack's i's directly (tail lanes zero-A).
#pragma unroll
                for (int j = 0; j < NJ; ++j)
                    sacc[j] = __builtin_amdgcn_mfma_f32_16x16x32_bf16(afull[j], xv, sacc[j], 0, 0, 0);
            } else {
#pragma unroll
                for (int q = 0; q < 4; ++q) {
                    if (q < nq) {
                        const bf16x8 bq = (kg == q) ? xv : zerob;  // isolate i
                        f32x4 uh[NJ];
#pragma unroll
                        for (int j = 0; j < NJ; ++j)
                            uh[j] = __builtin_amdgcn_mfma_f32_16x16x32_bf16(afull[j], bq, zero, 0, 0, 0);

                        float bd[NJ];
#pragma unroll
                        for (int j = 0; j < NJ; ++j) {
                            float v = uh[j][0] * vs[j][0] + uh[j][1] * vs[j][1]
                                    + uh[j][2] * vs[j][2] + uh[j][3] * vs[j][3];
                            v += __shfl_xor(v, 16, 64);   // reduce the 4 d-quads
                            v += __shfl_xor(v, 32, 64);
                            bd[j] = v;
                        }
                        float m01 = fmaxf(bd[0], bd[1]), m23 = fmaxf(bd[2], bd[3]);
                        float m45 = fmaxf(bd[4], bd[5]), m67 = fmaxf(bd[6], bd[7]);
                        float m89 = fmaxf(bd[8], bd[9]);
                        float m = fmaxf(fmaxf(fmaxf(m01, m23), fmaxf(m45, m67)), m89);
#pragma unroll
                        for (int j = 0; j < NJ; ++j) bd[j] = __expf(bd[j] - m);
                        float Z = ((bd[0] + bd[1]) + (bd[2] + bd[3]))
                                + ((bd[4] + bd[5]) + (bd[6] + bd[7])) + (bd[8] + bd[9]);
                        const float rZ = 1.f / Z;
#pragma unroll
                        for (int j = 0; j < NJ; ++j) {
                            const float c = bd[j] * rZ;
                            sacc[j] += c * uh[j];
                        }
                    }
                }
            }
        }

        // partials: bf16, block-private slice (L2-resident 10.5MB buffer)
        unsigned short* pp = part + (size_t)igc * 81920 + (size_t)b * 160 + kg * 4;
#pragma unroll
        for (int j = 0; j < NJ; ++j) {
            ushort4 o;
            o.x = f2bf(sacc[j][0]); o.y = f2bf(sacc[j][1]);
            o.z = f2bf(sacc[j][2]); o.w = f2bf(sacc[j][3]);
            *(ushort4*)(pp + j * 16) = o;
        }

        grid.sync();   // partials visible grid-wide

        if (gt < 81920) {   // squash: gt = b*160 + j*16 + d
            const unsigned short* p = part + gt;
            float a0 = 0.f, a1 = 0.f, a2 = 0.f, a3 = 0.f;
#pragma unroll 4
            for (int c = 0; c < NIGC; c += 4) {
                a0 += bf2f(p[(size_t)c * 81920]);
                a1 += bf2f(p[(size_t)(c + 1) * 81920]);
                a2 += bf2f(p[(size_t)(c + 2) * 81920]);
                a3 += bf2f(p[(size_t)(c + 3) * 81920]);
            }
            float s = ((a0 + a1) + (a2 + a3)) * (iter == 0 ? 0.1f : 1.0f);
            float sq = s * s;
            sq += __shfl_xor(sq, 1, 64);
            sq += __shfl_xor(sq, 2, 64);
            sq += __shfl_xor(sq, 4, 64);
            sq += __shfl_xor(sq, 8, 64);
            const float sc = sq / ((1.f + sq) * sqrtf(sq + EPS_));
            const float v  = sc * s;
            if (iter < 2) { vr += v; vsum_g[gt] = vr; }
            else          out[gt] = v;
        }
        if (iter < 2) grid.sync();   // vsum visible before next iteration
    }
}

// ============================ FALLBACK (R15, proven 163.8us) ============================

template <int MODE>
__global__ __launch_bounds__(256, 2)
void caps_fb(const unsigned short* __restrict__ xb,
             const unsigned short* __restrict__ wb,
             const float* __restrict__ vsum_g,
             unsigned short* __restrict__ part)
{
    __shared__ __align__(16) char smem[30368];
    unsigned short* wl = (unsigned short*)smem;
    unsigned short* xl = (unsigned short*)(smem + 20608);

    const int tid = threadIdx.x, lane = tid & 63, w = tid >> 6;
    const int bl = lane & 15, kg = lane >> 4;
    const int bg = blockIdx.x, ig = blockIdx.y;
    const int i0 = ig * 8, b0 = bg * 64;
    const int b  = b0 + w * 16 + bl;
    const int brow = w * 16 + bl;

#pragma unroll
    for (int r = 0; r < 5; ++r) {
        int g  = tid + r * 256;
        int il = g / 160, rem = g - il * 160;
        *(u16x8*)(wl + (il * 161 + rem) * 8) = *(const u16x8*)(
            wb + ((size_t)(rem >> 4) * NI + (i0 + il)) * 128 + (rem & 15) * 8);
    }
#pragma unroll
    for (int r = 0; r < 2; ++r) {
        int g = tid + r * 256;
        if (g < 512) {
            int br = g >> 3, il = g & 7;
            *(u16x8*)(xl + (br * 9 + il) * 8) =
                *(const u16x8*)(xb + ((size_t)(b0 + br) * NI + i0 + il) * 8);
        }
    }

    f32x4 vs[NJ];
    if (MODE == 1) {
#pragma unroll
        for (int j = 0; j < NJ; ++j)
            vs[j] = *(const f32x4*)(vsum_g + (size_t)b * 160 + j * 16 + kg * 4);
    }
    __syncthreads();

    const f32x4  zero  = {0.f, 0.f, 0.f, 0.f};
    const bf16x8 zerob = {0, 0, 0, 0, 0, 0, 0, 0};
    f32x4 sacc[NJ];
#pragma unroll
    for (int j = 0; j < NJ; ++j) sacc[j] = zero;

#pragma unroll
    for (int t4 = 0; t4 < 2; ++t4) {
        bf16x8 afull[NJ];
#pragma unroll
        for (int j = 0; j < NJ; ++j)
            afull[j] = *(const bf16x8*)(wl + (((t4 * 4 + kg) * 161) + j * 16 + bl) * 8);
        bf16x8 xv = *(const bf16x8*)(xl + (brow * 9 + t4 * 4 + kg) * 8);

        if (MODE == 0) {
#pragma unroll
            for (int j = 0; j < NJ; ++j)
                sacc[j] = __builtin_amdgcn_mfma_f32_16x16x32_bf16(afull[j], xv, sacc[j], 0, 0, 0);
        } else {
#pragma unroll
            for (int q = 0; q < 4; ++q) {
                const bf16x8 bq = (kg == q) ? xv : zerob;
                f32x4 uh[NJ];
#pragma unroll
                for (int j = 0; j < NJ; ++j)
                    uh[j] = __builtin_amdgcn_mfma_f32_16x16x32_bf16(afull[j], bq, zero, 0, 0, 0);
                float bd[NJ];
#pragma unroll
                for (int j = 0; j < NJ; ++j) {
                    float v = uh[j][0] * vs[j][0] + uh[j][1] * vs[j][1]
                            + uh[j][2] * vs[j][2] + uh[j][3] * vs[j][3];
                    v += __shfl_xor(v, 16, 64);
                    v += __shfl_xor(v, 32, 64);
                    bd[j] = v;
                }
                float m = fmaxf(fmaxf(fmaxf(fmaxf(bd[0], bd[1]), fmaxf(bd[2], bd[3])),
                                      fmaxf(fmaxf(bd[4], bd[5]), fmaxf(bd[6], bd[7]))),
                                fmaxf(bd[8], bd[9]));
#pragma unroll
                for (int j = 0; j < NJ; ++j) bd[j] = __expf(bd[j] - m);
                float Z = ((bd[0] + bd[1]) + (bd[2] + bd[3]))
                        + ((bd[4] + bd[5]) + (bd[6] + bd[7])) + (bd[8] + bd[9]);
                const float rZ = 1.f / Z;
#pragma unroll
                for (int j = 0; j < NJ; ++j) {
                    const float c = bd[j] * rZ;
                    sacc[j] += c * uh[j];
                }
            }
        }
    }

    __syncthreads();
    unsigned short* s16 = (unsigned short*)smem;
#pragma unroll
    for (int j = 0; j < NJ; ++j) {
        ushort4 o;
        o.x = f2bf(sacc[j][0]); o.y = f2bf(sacc[j][1]);
        o.z = f2bf(sacc[j][2]); o.w = f2bf(sacc[j][3]);
        *(ushort4*)(s16 + brow * 168 + j * 16 + kg * 4) = o;
    }
    __syncthreads();
    unsigned short* pp = part + ((size_t)ig * NB + b0) * 160;
#pragma unroll
    for (int r = 0; r < 5; ++r) {
        int idx = tid + r * 256;
        int row = idx / 20, ch = idx - row * 20;
        *(u16x8*)(pp + idx * 8) = *(const u16x8*)(s16 + row * 168 + ch * 8);
    }
}

__global__ __launch_bounds__(256)
void squash_fb(const unsigned short* __restrict__ part,
               float* __restrict__ vsum_g, float* __restrict__ out,
               float alpha, int mode)
{
    const int t = blockIdx.x * 256 + threadIdx.x;
    const unsigned short* p = part + t;
    float a0 = 0.f, a1 = 0.f, a2 = 0.f, a3 = 0.f;
#pragma unroll 4
    for (int ig = 0; ig < NIGB; ig += 4) {
        a0 += bf2f(p[(size_t)ig * 81920]);
        a1 += bf2f(p[(size_t)(ig + 1) * 81920]);
        a2 += bf2f(p[(size_t)(ig + 2) * 81920]);
        a3 += bf2f(p[(size_t)(ig + 3) * 81920]);
    }
    const float s = ((a0 + a1) + (a2 + a3)) * alpha;
    float sq = s * s;
    sq += __shfl_xor(sq, 1, 64);
    sq += __shfl_xor(sq, 2, 64);
    sq += __shfl_xor(sq, 4, 64);
    sq += __shfl_xor(sq, 8, 64);
    const float sc = sq / ((1.f + sq) * sqrtf(sq + EPS_));
    const float v  = sc * s;
    if (mode == 0)      vsum_g[t] = v;
    else if (mode == 1) vsum_g[t] += v;
    else                out[t] = v;
}

// ============================ launch ============================

extern "C" void kernel_launch(void* const* d_in, const int* in_sizes, int n_in,
                              void* d_out, int out_size, void* d_ws, size_t ws_size,
                              hipStream_t stream)
{
    const float* inp = (const float*)d_in[0];
    const float* Wg  = (const float*)d_in[1];
    float* out = (float*)d_out;

    unsigned short* xbp  = (unsigned short*)d_ws;
    unsigned short* wbp  = xbp + XB_ELEMS;
    unsigned short* part = wbp + WB_ELEMS;                    // max(64,144)-slice bf16
    float* vsum = (float*)(part + (size_t)NIGB * NB * 160);   // f32 [512][160]

    conv_bf16<<<(XQ + WQ + 255) / 256, 256, 0, stream>>>(inp, Wg, xbp, wbp);

    void* args[] = {(void*)&xbp, (void*)&wbp, (void*)&part, (void*)&vsum, (void*)&out};
    hipError_t rc = hipLaunchCooperativeKernel((const void*)caps_fused,
                                               dim3(512), dim3(256), args, 0, stream);
    if (rc != hipSuccess) {
        // fallback: proven R15 3-pass path
        dim3 grid(8, NIGB);
        caps_fb<0><<<grid, 256, 0, stream>>>(xbp, wbp, nullptr, part);
        squash_fb<<<320, 256, 0, stream>>>(part, vsum, out, 0.1f, 0);
        caps_fb<1><<<grid, 256, 0, stream>>>(xbp, wbp, vsum, part);
        squash_fb<<<320, 256, 0, stream>>>(part, vsum, out, 1.0f, 1);
        caps_fb<1><<<grid, 256, 0, stream>>>(xbp, wbp, vsum, part);
        squash_fb<<<320, 256, 0, stream>>>(part, vsum, out, 1.0f, 2);
    }
}

// Round 18
// 156.314 us; speedup vs baseline: 2.8784x; 2.8784x over previous
//
#include <hip/hip_runtime.h>

// DigiCaps dynamic routing — R15 base + fp16-packed logit butterfly.
// inputs [512,1152,8] f32, W [10,1152,16,8] f32, out v [512,10,16] f32.
// u_hat[b,j,i,d] = sum_k x[b,i,k] W[j,i,d,k]; logits b_t = u_hat . vsum
// (vsum = running sum of v's) -> u_hat never materialized.
//
// R16 post-mortem: cooperative grid.sync costs ~100us/sync on 512 blocks —
// fusion reverted. R12 ord-forensics: MODE0 == MODE1 == 46us (light body ==
// heavy body) -> pass wall is the common skeleton; biggest unattacked DS
// consumer is the 160 bpermutes/wave of the logit butterfly. R17 = R15
// (measured best) with MODE1's reduction repacked: logit pairs -> fp16x2
// (cvt_pkrtz), butterfly = 10 shfl + 10 v_pk_add_f16 (was 20 shfl + 20
// adds), max-subtraction dropped (|logit| <= ~3, exp safe; fp16 rel 5e-4).
// R17b: fix h16x2 element type to __fp16 (cvt_pkrtz's return type).
// MFMA f32_16x16x32_bf16, C-layout: lane&15=b(col), (lane>>4)*4+reg=d(row).
// absmax ~4e-3 (threshold 17.5e-3).

#define NB 512
#define NI 1152
#define NJ 10
#define ND 16

typedef short          bf16x8 __attribute__((ext_vector_type(8)));
typedef unsigned short u16x8  __attribute__((ext_vector_type(8)));
typedef float          f32x4  __attribute__((ext_vector_type(4)));
typedef __fp16         h16x2  __attribute__((ext_vector_type(2)));

constexpr float EPS_ = 1e-7f;

constexpr size_t XB_ELEMS = (size_t)NB * NI * 8;       // bf16
constexpr size_t WB_ELEMS = (size_t)NJ * NI * ND * 8;  // bf16
constexpr int    XQ = 1179648;                         // x float4 quads
constexpr int    WQ = 368640;                          // W float4 quads
constexpr int    NIGB = 144;                           // i-groups of 8

__device__ inline unsigned short f2bf(float f) {   // RNE f32->bf16
    unsigned u = __float_as_uint(f);
    return (unsigned short)((u + 0x7fffu + ((u >> 16) & 1u)) >> 16);
}
__device__ inline float bf2f(unsigned short u) {
    return __uint_as_float((unsigned)u << 16);
}

__global__ __launch_bounds__(256)
void conv_bf16(const float* __restrict__ x, const float* __restrict__ Wg,
               unsigned short* __restrict__ xb, unsigned short* __restrict__ wb)
{
    int t = blockIdx.x * 256 + threadIdx.x;
    if (t < XQ) {
        float4 v = ((const float4*)x)[t];
        ushort4 o; o.x=f2bf(v.x); o.y=f2bf(v.y); o.z=f2bf(v.z); o.w=f2bf(v.w);
        ((ushort4*)xb)[t] = o;
    } else if (t - XQ < WQ) {
        int u = t - XQ;
        float4 v = ((const float4*)Wg)[u];
        ushort4 o; o.x=f2bf(v.x); o.y=f2bf(v.y); o.z=f2bf(v.z); o.w=f2bf(v.w);
        ((ushort4*)wb)[u] = o;
    }
}

// Block: 64 b (4 waves x 16) x 8 i (two 4-i K-packs). LDS ~30KB.
template <int MODE>
__global__ __launch_bounds__(256, 2)
void caps_pass(const unsigned short* __restrict__ xb,
               const unsigned short* __restrict__ wb,
               const float* __restrict__ vsum_g,
               unsigned short* __restrict__ part)
{
    // wl: granule g = il*161 + j*16 + d (pad granule breaks kg-group
    // aliasing). xl: row stride 9 granules. Epilogue reuses smem as
    // bf16 s16[64][168].
    __shared__ __align__(16) char smem[30368];
    unsigned short* wl = (unsigned short*)smem;                 // 1288 granules
    unsigned short* xl = (unsigned short*)(smem + 20608);       // 576 granules

    const int tid = threadIdx.x, lane = tid & 63, w = tid >> 6;
    const int bl = lane & 15, kg = lane >> 4;
    const int bg = blockIdx.x, ig = blockIdx.y;
    const int i0 = ig * 8, b0 = bg * 64;
    const int b  = b0 + w * 16 + bl;
    const int brow = w * 16 + bl;

    // stage W: 1280 real granules -> slot il*161 + rem
#pragma unroll
    for (int r = 0; r < 5; ++r) {
        int g  = tid + r * 256;
        int il = g / 160, rem = g - il * 160;
        const unsigned short* src =
            wb + ((size_t)(rem >> 4) * NI + (i0 + il)) * 128 + (rem & 15) * 8;
        *(u16x8*)(wl + (il * 161 + rem) * 8) = *(const u16x8*)src;
    }
    // stage x: slot brow*9 + il  <-  x[b0+brow, i0+il, 0:8]
#pragma unroll
    for (int r = 0; r < 2; ++r) {
        int g = tid + r * 256;
        if (g < 512) {
            int br = g >> 3, il = g & 7;
            *(u16x8*)(xl + (br * 9 + il) * 8) =
                *(const u16x8*)(xb + ((size_t)(b0 + br) * NI + i0 + il) * 8);
        }
    }

    f32x4 vs[NJ];
    if (MODE == 1) {
#pragma unroll
        for (int j = 0; j < NJ; ++j)
            vs[j] = *(const f32x4*)(vsum_g + (size_t)b * 160 + j * 16 + kg * 4);
    }

    __syncthreads();

    const f32x4  zero  = {0.f, 0.f, 0.f, 0.f};
    const bf16x8 zerob = {0, 0, 0, 0, 0, 0, 0, 0};
    f32x4 sacc[NJ];
#pragma unroll
    for (int j = 0; j < NJ; ++j) sacc[j] = zero;

#pragma unroll
    for (int t4 = 0; t4 < 2; ++t4) {
        // A-frags: lane (kg,bl) = W[i0+t4*4+kg, j, d=bl, 0:8] — K=32 packed,
        // all 64 lanes real; 10 reads per FOUR i's.
        bf16x8 afull[NJ];
#pragma unroll
        for (int j = 0; j < NJ; ++j)
            afull[j] = *(const bf16x8*)(wl + (((t4 * 4 + kg) * 161) + j * 16 + bl) * 8);
        bf16x8 xv = *(const bf16x8*)(xl + (brow * 9 + t4 * 4 + kg) * 8);

        if (MODE == 0) {
#pragma unroll
            for (int j = 0; j < NJ; ++j)
                sacc[j] = __builtin_amdgcn_mfma_f32_16x16x32_bf16(afull[j], xv, sacc[j], 0, 0, 0);
        } else {
#pragma unroll
            for (int q = 0; q < 4; ++q) {
                const bf16x8 bq = (kg == q) ? xv : zerob;   // isolate i = i0+t4*4+q
                f32x4 uh[NJ];
#pragma unroll
                for (int j = 0; j < NJ; ++j)
                    uh[j] = __builtin_amdgcn_mfma_f32_16x16x32_bf16(afull[j], bq, zero, 0, 0, 0);

                // per-lane partial dots over this lane's 4 d's (f32)
                float bd[NJ];
#pragma unroll
                for (int j = 0; j < NJ; ++j)
                    bd[j] = uh[j][0] * vs[j][0] + uh[j][1] * vs[j][1]
                          + uh[j][2] * vs[j][2] + uh[j][3] * vs[j][3];

                // fp16x2-packed butterfly over the 4 d-quad lane groups:
                // 10 shfl + 10 pk_add (was 20 shfl + 20 adds).
                h16x2 pk[5];
#pragma unroll
                for (int jp = 0; jp < 5; ++jp)
                    pk[jp] = __builtin_amdgcn_cvt_pkrtz(bd[2 * jp], bd[2 * jp + 1]);
#pragma unroll
                for (int jp = 0; jp < 5; ++jp) {
                    float f = __shfl_xor(__builtin_bit_cast(float, pk[jp]), 16, 64);
                    pk[jp] = pk[jp] + __builtin_bit_cast(h16x2, f);
                }
#pragma unroll
                for (int jp = 0; jp < 5; ++jp) {
                    float f = __shfl_xor(__builtin_bit_cast(float, pk[jp]), 32, 64);
                    pk[jp] = pk[jp] + __builtin_bit_cast(h16x2, f);
                }

                // softmax over j, no max-subtract (|logit| <= ~3, exp safe)
                float e[NJ];
#pragma unroll
                for (int jp = 0; jp < 5; ++jp) {
                    e[2 * jp]     = __expf((float)pk[jp][0]);
                    e[2 * jp + 1] = __expf((float)pk[jp][1]);
                }
                float Z = ((e[0] + e[1]) + (e[2] + e[3]))
                        + ((e[4] + e[5]) + (e[6] + e[7])) + (e[8] + e[9]);
                const float rZ = 1.f / Z;
#pragma unroll
                for (int j = 0; j < NJ; ++j) {
                    const float c = e[j] * rZ;
                    sacc[j] += c * uh[j];
                }
            }
        }
    }

    // epilogue: sacc -> bf16 LDS bounce -> dense contiguous bf16 partials
    __syncthreads();
    unsigned short* s16 = (unsigned short*)smem;   // [64][168]
#pragma unroll
    for (int j = 0; j < NJ; ++j) {
        ushort4 o;
        o.x = f2bf(sacc[j][0]); o.y = f2bf(sacc[j][1]);
        o.z = f2bf(sacc[j][2]); o.w = f2bf(sacc[j][3]);
        *(ushort4*)(s16 + brow * 168 + j * 16 + kg * 4) = o;
    }
    __syncthreads();
    unsigned short* pp = part + ((size_t)ig * NB + b0) * 160;
#pragma unroll
    for (int r = 0; r < 5; ++r) {
        int idx = tid + r * 256;                 // 1280 ushort8 chunks = 64x160
        int row = idx / 20, ch = idx - row * 20;
        *(u16x8*)(pp + idx * 8) = *(const u16x8*)(s16 + row * 168 + ch * 8);
    }
}

// Sum 144 bf16 ig-partials, scale, squash over d (16-lane shfl), update vsum/out.
__global__ __launch_bounds__(256)
void squash_reduce(const unsigned short* __restrict__ part,
                   float* __restrict__ vsum_g, float* __restrict__ out,
                   float alpha, int mode)
{
    const int t = blockIdx.x * 256 + threadIdx.x;   // < 81920 = b*160 + j*16 + d
    const unsigned short* p = part + t;
    float a0 = 0.f, a1 = 0.f, a2 = 0.f, a3 = 0.f;
#pragma unroll 4
    for (int ig = 0; ig < NIGB; ig += 4) {
        a0 += bf2f(p[(size_t)ig * 81920]);
        a1 += bf2f(p[(size_t)(ig + 1) * 81920]);
        a2 += bf2f(p[(size_t)(ig + 2) * 81920]);
        a3 += bf2f(p[(size_t)(ig + 3) * 81920]);
    }
    const float s = ((a0 + a1) + (a2 + a3)) * alpha;

    float sq = s * s;
    sq += __shfl_xor(sq, 1, 64);
    sq += __shfl_xor(sq, 2, 64);
    sq += __shfl_xor(sq, 4, 64);
    sq += __shfl_xor(sq, 8, 64);
    const float sc = sq / ((1.f + sq) * sqrtf(sq + EPS_));
    const float v  = sc * s;

    if (mode == 0)      vsum_g[t] = v;
    else if (mode == 1) vsum_g[t] += v;
    else                out[t] = v;
}

extern "C" void kernel_launch(void* const* d_in, const int* in_sizes, int n_in,
                              void* d_out, int out_size, void* d_ws, size_t ws_size,
                              hipStream_t stream)
{
    const float* inp = (const float*)d_in[0];
    const float* Wg  = (const float*)d_in[1];
    float* out = (float*)d_out;

    unsigned short* xbp  = (unsigned short*)d_ws;
    unsigned short* wbp  = xbp + XB_ELEMS;
    unsigned short* part = wbp + WB_ELEMS;                    // [144][512][160] bf16
    float* vsum = (float*)(part + (size_t)NIGB * NB * 160);   // [512][10][16] f32

    conv_bf16<<<(XQ + WQ + 255) / 256, 256, 0, stream>>>(inp, Wg, xbp, wbp);

    dim3 grid(8, NIGB);   // (8,144) = 1152 blocks
    // iter 0: c uniform 1/10 (folded into alpha); K=32 contracts 4 i's exactly
    caps_pass<0><<<grid, 256, 0, stream>>>(xbp, wbp, nullptr, part);
    squash_reduce<<<320, 256, 0, stream>>>(part, vsum, out, 0.1f, 0);
    // iter 1: logits = u_hat . v0
    caps_pass<1><<<grid, 256, 0, stream>>>(xbp, wbp, vsum, part);
    squash_reduce<<<320, 256, 0, stream>>>(part, vsum, out, 1.0f, 1);
    // iter 2: logits = u_hat . (v0+v1)
    caps_pass<1><<<grid, 256, 0, stream>>>(xbp, wbp, vsum, part);
    squash_reduce<<<320, 256, 0, stream>>>(part, vsum, out, 1.0f, 2);
}